// Round 1
// baseline (1461.812 us; speedup 1.0000x reference)
//
#include <hip/hip_runtime.h>
#include <hip/hip_bf16.h>

#define NN 8192
#define FF 512
#define HH 512

typedef __attribute__((ext_vector_type(4))) float f32x4;
typedef __attribute__((ext_vector_type(8))) __bf16 bf16x8;

__device__ __forceinline__ unsigned short f2bf(float f) {
    union { float f; unsigned int u; } c; c.f = f;
    unsigned int u = c.u;
    return (unsigned short)((u + 0x7FFFu + ((u >> 16) & 1u)) >> 16);
}

// ---------------- graph prep ----------------

__global__ void count2_k(const int* __restrict__ src, const int* __restrict__ dst, int E,
                         int* __restrict__ cs, int* __restrict__ cd) {
    int i = blockIdx.x * blockDim.x + threadIdx.x;
    if (i < E) {
        atomicAdd(&cs[src[i]], 1);
        atomicAdd(&cd[dst[i]], 1);
    }
}

__global__ void dinv4_k(const int* c1s, const int* c1d, const int* c2s, const int* c2d,
                        float* d1s, float* d1d, float* d2s, float* d2d) {
    int n = blockIdx.x * blockDim.x + threadIdx.x;
    if (n < NN) {
        d1s[n] = rsqrtf(fmaxf((float)c1s[n], 1.f));
        d1d[n] = rsqrtf(fmaxf((float)c1d[n], 1.f));
        d2s[n] = rsqrtf(fmaxf((float)c2s[n], 1.f));
        d2d[n] = rsqrtf(fmaxf((float)c2d[n], 1.f));
    }
}

// exclusive scan of 8192 ints, single block of 1024 threads
__global__ void scan8192_k(const int* __restrict__ cnt, int* __restrict__ rp) {
    __shared__ int ts[1024];
    int t = threadIdx.x;
    int base = t * 8;
    int loc[8]; int s = 0;
#pragma unroll
    for (int j = 0; j < 8; j++) { loc[j] = s; s += cnt[base + j]; }
    ts[t] = s;
    __syncthreads();
    for (int off = 1; off < 1024; off <<= 1) {
        int v = 0;
        if (t >= off) v = ts[t - off];
        __syncthreads();
        if (t >= off) ts[t] += v;
        __syncthreads();
    }
    int pre = (t == 0) ? 0 : ts[t - 1];
#pragma unroll
    for (int j = 0; j < 8; j++) rp[base + j] = pre + loc[j];
    if (t == 1023) rp[8192] = ts[1023];
}

__global__ void copy_i_k(const int* __restrict__ a, int* __restrict__ b, int n) {
    int i = blockIdx.x * blockDim.x + threadIdx.x;
    if (i < n) b[i] = a[i];
}

__global__ void fill_k(const int* __restrict__ src, const int* __restrict__ dst, int E,
                       int* __restrict__ woff, int* __restrict__ col) {
    int i = blockIdx.x * blockDim.x + threadIdx.x;
    if (i < E) {
        int p = atomicAdd(&woff[dst[i]], 1);
        col[p] = src[i];
    }
}

// ---------------- input build ----------------

__global__ void copy_f4_k(const float4* __restrict__ a, float4* __restrict__ b, int n4) {
    for (int i = blockIdx.x * blockDim.x + threadIdx.x; i < n4; i += gridDim.x * blockDim.x)
        b[i] = a[i];
}

__global__ void set_noise_k(const int* __restrict__ nn, const int* __restrict__ ns,
                            const float4* __restrict__ attr, float4* __restrict__ x) {
    int b = blockIdx.x, t = threadIdx.x; // 128 threads: 128 float4 = 512 floats
    int d = nn[b], s = ns[b];
    x[(size_t)d * 128 + t] = attr[(size_t)s * 128 + t];
}

__global__ void set_token_k(const int* __restrict__ tn, const float4* __restrict__ mask,
                            float4* __restrict__ x) {
    int b = blockIdx.x, t = threadIdx.x;
    x[(size_t)tn[b] * 128 + t] = mask[t];
}

// transpose W (NL,H,H) -> Wt (NL, H(out-col), H(k)) in bf16
__global__ void wtrans_k(const float* __restrict__ W, unsigned short* __restrict__ Wt) {
    __shared__ float tile[32][33];
    int l = blockIdx.z;
    int k0 = blockIdx.x * 32, j0 = blockIdx.y * 32;
    const float* Wl = W + (size_t)l * HH * HH;
    unsigned short* Wtl = Wt + (size_t)l * HH * HH;
    for (int i = threadIdx.y; i < 32; i += 8)
        tile[i][threadIdx.x] = Wl[(size_t)(k0 + i) * HH + j0 + threadIdx.x];
    __syncthreads();
    for (int i = threadIdx.y; i < 32; i += 8)
        Wtl[(size_t)(j0 + i) * HH + k0 + threadIdx.x] = f2bf(tile[threadIdx.x][i]);
}

// ---------------- SpMM (segment_sum by dst via CSR), writes bf16 m ----------------

__global__ __launch_bounds__(256) void spmm_k(
    const float* __restrict__ h, const int* __restrict__ rp, const int* __restrict__ ci,
    const float* __restrict__ dsrc, const float* __restrict__ ddst,
    unsigned short* __restrict__ mout, int enc) {
    int lane = threadIdx.x & 63;
    int n = blockIdx.x * 4 + (threadIdx.x >> 6);
    int beg = rp[n], end = rp[n + 1];
    const float4* h4 = (const float4*)h;
    float a0 = 0, a1 = 0, a2 = 0, a3 = 0, a4 = 0, a5 = 0, a6 = 0, a7 = 0;
    for (int e = beg; e < end; ++e) {
        int s = ci[e];
        float w = enc ? dsrc[s] : 1.0f;
        float4 v0 = h4[(size_t)s * 128 + lane];
        float4 v1 = h4[(size_t)s * 128 + 64 + lane];
        a0 += v0.x * w; a1 += v0.y * w; a2 += v0.z * w; a3 += v0.w * w;
        a4 += v1.x * w; a5 += v1.y * w; a6 += v1.z * w; a7 += v1.w * w;
    }
    float sc = enc ? ddst[n] : 1.0f;
    unsigned short* mp = mout + (size_t)n * HH;
    ushort4 o0; o0.x = f2bf(a0 * sc); o0.y = f2bf(a1 * sc); o0.z = f2bf(a2 * sc); o0.w = f2bf(a3 * sc);
    ushort4 o1; o1.x = f2bf(a4 * sc); o1.y = f2bf(a5 * sc); o1.z = f2bf(a6 * sc); o1.w = f2bf(a7 * sc);
    *reinterpret_cast<ushort4*>(mp + lane * 4) = o0;
    *reinterpret_cast<ushort4*>(mp + 256 + lane * 4) = o1;
}

// ---------------- GEMM: C = A(MxK) @ Bt(NcolsxK)^T, bf16 MFMA ----------------
// MODE 0: C -> hpre with bias + prelu(ain).  MODE 1: accumulate (C - matrix)^2.

__device__ __forceinline__ bf16x8 ld_frag(const unsigned short* p) {
    union { ushort4 s[2]; bf16x8 v; } u;
    u.s[0] = *reinterpret_cast<const ushort4*>(p);
    u.s[1] = *reinterpret_cast<const ushort4*>(p + 4);
    return u.v;
}

template <int MODE>
__global__ __launch_bounds__(256) void gemm_bt_k(
    const unsigned short* __restrict__ A,   // M x 512 bf16 row-major
    const unsigned short* __restrict__ Bt,  // Ncols x 512 bf16 row-major
    float* __restrict__ Cout,               // MODE 0
    const float* __restrict__ bias,         // MODE 0 (pre-offset, len 512)
    const float* __restrict__ ain_p,        // MODE 0 (pre-offset scalar)
    const float* __restrict__ matrix,       // MODE 1
    float* __restrict__ loss_p)             // MODE 1
{
    __shared__ unsigned short sA[128 * 40];
    __shared__ unsigned short sB[128 * 40];
    int tid = threadIdx.x, lane = tid & 63, wid = tid >> 6;
    int wm = wid >> 1, wn = wid & 1;
    size_t row0 = (size_t)blockIdx.x * 128, col0 = (size_t)blockIdx.y * 128;

    f32x4 acc[4][4];
#pragma unroll
    for (int i = 0; i < 4; i++)
#pragma unroll
        for (int j = 0; j < 4; j++) acc[i][j] = f32x4{0.f, 0.f, 0.f, 0.f};

    for (int k0 = 0; k0 < 512; k0 += 32) {
#pragma unroll
        for (int i = 0; i < 2; i++) {
            int q = tid + 256 * i;       // 0..511
            int r = q >> 2, c = q & 3;   // row in tile, 16B chunk
            uint4 va = *reinterpret_cast<const uint4*>(A + (row0 + r) * 512 + k0 + c * 8);
            uint4 vb = *reinterpret_cast<const uint4*>(Bt + (col0 + r) * 512 + k0 + c * 8);
            unsigned short* pa = sA + r * 40 + c * 8;
            unsigned short* pb = sB + r * 40 + c * 8;
            *reinterpret_cast<uint2*>(pa) = make_uint2(va.x, va.y);
            *reinterpret_cast<uint2*>(pa + 4) = make_uint2(va.z, va.w);
            *reinterpret_cast<uint2*>(pb) = make_uint2(vb.x, vb.y);
            *reinterpret_cast<uint2*>(pb + 4) = make_uint2(vb.z, vb.w);
        }
        __syncthreads();
        bf16x8 af[4], bfr[4];
#pragma unroll
        for (int mi = 0; mi < 4; mi++)
            af[mi] = ld_frag(sA + (wm * 64 + mi * 16 + (lane & 15)) * 40 + (lane >> 4) * 8);
#pragma unroll
        for (int nj = 0; nj < 4; nj++)
            bfr[nj] = ld_frag(sB + (wn * 64 + nj * 16 + (lane & 15)) * 40 + (lane >> 4) * 8);
#pragma unroll
        for (int mi = 0; mi < 4; mi++)
#pragma unroll
            for (int nj = 0; nj < 4; nj++)
                acc[mi][nj] = __builtin_amdgcn_mfma_f32_16x16x32_bf16(af[mi], bfr[nj], acc[mi][nj], 0, 0, 0);
        __syncthreads();
    }

    if (MODE == 0) {
        float ain = ain_p[0];
#pragma unroll
        for (int mi = 0; mi < 4; mi++)
#pragma unroll
            for (int nj = 0; nj < 4; nj++) {
                size_t gr = row0 + wm * 64 + mi * 16 + (lane >> 4) * 4;
                size_t gc = col0 + wn * 64 + nj * 16 + (lane & 15);
                float bv = bias[gc];
#pragma unroll
                for (int r = 0; r < 4; r++) {
                    float v = acc[mi][nj][r] + bv;
                    v = (v >= 0.f) ? v : ain * v;
                    Cout[(gr + r) * 512 + gc] = v;
                }
            }
    } else {
        float ls = 0.f;
#pragma unroll
        for (int mi = 0; mi < 4; mi++)
#pragma unroll
            for (int nj = 0; nj < 4; nj++) {
                size_t gi = row0 + wm * 64 + mi * 16 + (lane >> 4) * 4;
                size_t gj = col0 + wn * 64 + nj * 16 + (lane & 15);
#pragma unroll
                for (int r = 0; r < 4; r++) {
                    float d = acc[mi][nj][r] - matrix[(gi + r) * NN + gj];
                    ls += d * d;
                }
            }
        for (int o = 32; o > 0; o >>= 1) ls += __shfl_xor(ls, o);
        if (lane == 0) atomicAdd(loss_p, ls);
    }
}

// ---------------- BN ----------------

__global__ __launch_bounds__(512) void colstats_k(const float* __restrict__ hpre,
                                                  float* __restrict__ psum, float* __restrict__ psq) {
    int t = threadIdx.x, b = blockIdx.x; // 64 blocks x 128 rows
    float s = 0, q = 0;
    const float* p = hpre + (size_t)b * 128 * 512 + t;
    for (int r = 0; r < 128; r++) { float v = p[(size_t)r * 512]; s += v; q += v * v; }
    psum[b * 512 + t] = s;
    psq[b * 512 + t] = q;
}

__global__ void make_st_k(const float* __restrict__ psum, const float* __restrict__ psq,
                          const float* __restrict__ g, const float* __restrict__ bb,
                          float* __restrict__ sc, float* __restrict__ sh) {
    int t = threadIdx.x; // 512
    float s = 0, q = 0;
    for (int b = 0; b < 64; b++) { s += psum[b * 512 + t]; q += psq[b * 512 + t]; }
    float mean = s / 8192.f;
    float var = fmaxf(q / 8192.f - mean * mean, 0.f);
    float scale = rsqrtf(var + 1e-5f) * g[t];
    sc[t] = scale;
    sh[t] = bb[t] - mean * scale;
}

__global__ __launch_bounds__(256) void bn_apply_k(const float* __restrict__ hpre,
                                                  const float* __restrict__ sc, const float* __restrict__ sh,
                                                  const float* __restrict__ aout_p, float* __restrict__ hout) {
    float a = aout_p[0];
    const float4* hp = (const float4*)hpre;
    float4* ho = (float4*)hout;
    int n4 = NN * HH / 4;
    for (int i = blockIdx.x * blockDim.x + threadIdx.x; i < n4; i += gridDim.x * blockDim.x) {
        float4 v = hp[i];
        int col = (i & 127) * 4;
        float y0 = v.x * sc[col + 0] + sh[col + 0]; y0 = (y0 >= 0.f) ? y0 : a * y0;
        float y1 = v.y * sc[col + 1] + sh[col + 1]; y1 = (y1 >= 0.f) ? y1 : a * y1;
        float y2 = v.z * sc[col + 2] + sh[col + 2]; y2 = (y2 >= 0.f) ? y2 : a * y2;
        float y3 = v.w * sc[col + 3] + sh[col + 3]; y3 = (y3 >= 0.f) ? y3 : a * y3;
        float4 o; o.x = y0; o.y = y1; o.z = y2; o.w = y3;
        ho[i] = o;
    }
}

// ---------------- losses ----------------

__global__ __launch_bounds__(256) void loss1_k(const float* __restrict__ h1, const float* __restrict__ attr,
                                               float* __restrict__ acc) {
    int lane = threadIdx.x & 63;
    int n = blockIdx.x * 4 + (threadIdx.x >> 6);
    const float4* a = (const float4*)(h1 + (size_t)n * 512);
    const float4* b = (const float4*)(attr + (size_t)n * 512);
    float xx = 0, yy = 0, xy = 0;
#pragma unroll
    for (int j = 0; j < 2; j++) {
        float4 va = a[lane + j * 64], vb = b[lane + j * 64];
        xx += va.x * va.x + va.y * va.y + va.z * va.z + va.w * va.w;
        yy += vb.x * vb.x + vb.y * vb.y + vb.z * vb.z + vb.w * vb.w;
        xy += va.x * vb.x + va.y * vb.y + va.z * vb.z + va.w * vb.w;
    }
    for (int o = 32; o > 0; o >>= 1) {
        xx += __shfl_xor(xx, o); yy += __shfl_xor(yy, o); xy += __shfl_xor(xy, o);
    }
    if (lane == 0) {
        float nx = fmaxf(sqrtf(xx), 1e-12f);
        float ny = fmaxf(sqrtf(yy), 1e-12f);
        float c = xy / (nx * ny);
        float d = 1.f - c;
        atomicAdd(acc, d * d * d);
    }
}

__global__ __launch_bounds__(256) void l2n_bf_k(const float* __restrict__ h, unsigned short* __restrict__ out) {
    int lane = threadIdx.x & 63;
    int n = blockIdx.x * 4 + (threadIdx.x >> 6);
    const float4* a = (const float4*)(h + (size_t)n * 512);
    float4 v0 = a[lane], v1 = a[lane + 64];
    float ss = v0.x * v0.x + v0.y * v0.y + v0.z * v0.z + v0.w * v0.w
             + v1.x * v1.x + v1.y * v1.y + v1.z * v1.z + v1.w * v1.w;
    for (int o = 32; o > 0; o >>= 1) ss += __shfl_xor(ss, o);
    float inv = 1.f / fmaxf(sqrtf(ss), 1e-12f);
    unsigned short* mp = out + (size_t)n * 512;
    ushort4 o0; o0.x = f2bf(v0.x * inv); o0.y = f2bf(v0.y * inv); o0.z = f2bf(v0.z * inv); o0.w = f2bf(v0.w * inv);
    ushort4 o1; o1.x = f2bf(v1.x * inv); o1.y = f2bf(v1.y * inv); o1.z = f2bf(v1.z * inv); o1.w = f2bf(v1.w * inv);
    *reinterpret_cast<ushort4*>(mp + lane * 4) = o0;
    *reinterpret_cast<ushort4*>(mp + 256 + lane * 4) = o1;
}

__global__ void final_k(const float* __restrict__ acc, float* __restrict__ out) {
    out[0] = 0.5f * (acc[0] / 8192.f) + 0.5f * (acc[1] / 67108864.f);
}

// ---------------- host ----------------

extern "C" void kernel_launch(void* const* d_in, const int* in_sizes, int n_in,
                              void* d_out, int out_size, void* d_ws, size_t ws_size,
                              hipStream_t stream) {
    const float* attr   = (const float*)d_in[0];
    const float* matrix = (const float*)d_in[1];
    const float* mask1  = (const float*)d_in[2];
    const int* src  = (const int*)d_in[3];
    const int* dst  = (const int*)d_in[4];
    const int* src2 = (const int*)d_in[5];
    const int* dst2 = (const int*)d_in[6];
    const int* token_nodes = (const int*)d_in[7];
    const int* noise_nodes = (const int*)d_in[8];
    const int* noise_src   = (const int*)d_in[9];
    const float* enc_W = (const float*)d_in[10];
    const float* enc_b = (const float*)d_in[11];
    const float* enc_ain = (const float*)d_in[12];
    const float* enc_g = (const float*)d_in[13];
    const float* enc_bb = (const float*)d_in[14];
    const float* enc_aout = (const float*)d_in[15];
    const float* d1_W = (const float*)d_in[16];
    const float* d1_b = (const float*)d_in[17];
    const float* d1_ain = (const float*)d_in[18];
    const float* d1_g = (const float*)d_in[19];
    const float* d1_bb = (const float*)d_in[20];
    const float* d1_aout = (const float*)d_in[21];
    const float* d2_W = (const float*)d_in[22];
    const float* d2_b = (const float*)d_in[23];
    const float* d2_ain = (const float*)d_in[24];
    const float* d2_g = (const float*)d_in[25];
    const float* d2_bb = (const float*)d_in[26];
    const float* d2_aout = (const float*)d_in[27];

    int EG = in_sizes[3], E2v = in_sizes[5], ntok = in_sizes[7], nnoise = in_sizes[8];

    char* w = (char*)d_ws;
    size_t off = 0;
    auto carve = [&](size_t bytes) -> void* {
        off = (off + 255) & ~(size_t)255;
        void* p = w + off;
        off += bytes;
        return p;
    };
    int* cnt1s = (int*)carve(NN * 4);
    int* cnt1d = (int*)carve(NN * 4);
    int* cnt2s = (int*)carve(NN * 4);
    int* cnt2d = (int*)carve(NN * 4);
    float* loss_acc = (float*)carve(256);
    size_t zero_end = off;

    int* rp1 = (int*)carve((NN + 1) * 4);
    int* rp2 = (int*)carve((NN + 1) * 4);
    int* woff1 = (int*)carve(NN * 4);
    int* woff2 = (int*)carve(NN * 4);
    float* dsrc1 = (float*)carve(NN * 4);
    float* ddst1 = (float*)carve(NN * 4);
    float* dsrc2 = (float*)carve(NN * 4);
    float* ddst2 = (float*)carve(NN * 4);
    int* col1 = (int*)carve((size_t)EG * 4);
    int* col2 = (int*)carve((size_t)E2v * 4);
    float* sc = (float*)carve(512 * 4);
    float* sh = (float*)carve(512 * 4);
    float* psum = (float*)carve(64 * 512 * 4);
    float* psq = (float*)carve(64 * 512 * 4);
    float* x = (float*)carve((size_t)NN * FF * 4);
    float* hA = (float*)carve((size_t)NN * HH * 4);
    float* hB = (float*)carve((size_t)NN * HH * 4);
    float* hpre = (float*)carve((size_t)NN * HH * 4);
    unsigned short* mbf = (unsigned short*)carve((size_t)NN * HH * 2);
    unsigned short* h2n = (unsigned short*)carve((size_t)NN * HH * 2);
    unsigned short* wtE = (unsigned short*)carve((size_t)2 * HH * HH * 2);
    unsigned short* wtD1 = (unsigned short*)carve((size_t)2 * HH * HH * 2);
    unsigned short* wtD2 = (unsigned short*)carve((size_t)2 * HH * HH * 2);

    hipMemsetAsync(d_ws, 0, zero_end, stream);

    count2_k<<<(EG + 255) / 256, 256, 0, stream>>>(src, dst, EG, cnt1s, cnt1d);
    count2_k<<<(E2v + 255) / 256, 256, 0, stream>>>(src2, dst2, E2v, cnt2s, cnt2d);
    dinv4_k<<<NN / 256, 256, 0, stream>>>(cnt1s, cnt1d, cnt2s, cnt2d, dsrc1, ddst1, dsrc2, ddst2);
    scan8192_k<<<1, 1024, 0, stream>>>(cnt1d, rp1);
    scan8192_k<<<1, 1024, 0, stream>>>(cnt2d, rp2);
    copy_i_k<<<NN / 256, 256, 0, stream>>>(rp1, woff1, NN);
    copy_i_k<<<NN / 256, 256, 0, stream>>>(rp2, woff2, NN);
    fill_k<<<(EG + 255) / 256, 256, 0, stream>>>(src, dst, EG, woff1, col1);
    fill_k<<<(E2v + 255) / 256, 256, 0, stream>>>(src2, dst2, E2v, woff2, col2);

    copy_f4_k<<<2048, 256, 0, stream>>>((const float4*)attr, (float4*)x, NN * FF / 4);
    set_noise_k<<<nnoise, 128, 0, stream>>>(noise_nodes, noise_src, (const float4*)attr, (float4*)x);
    set_token_k<<<ntok, 128, 0, stream>>>(token_nodes, (const float4*)mask1, (float4*)x);

    wtrans_k<<<dim3(16, 16, 2), dim3(32, 8), 0, stream>>>(enc_W, wtE);
    wtrans_k<<<dim3(16, 16, 2), dim3(32, 8), 0, stream>>>(d1_W, wtD1);
    wtrans_k<<<dim3(16, 16, 2), dim3(32, 8), 0, stream>>>(d2_W, wtD2);

    auto run_layer = [&](const float* hin, float* hout, const int* rp, const int* ci,
                         const float* dsrc, const float* ddst, int enc,
                         const unsigned short* Wt, const float* b, const float* ain,
                         const float* g, const float* bbp, const float* aout, int layer) {
        spmm_k<<<NN / 4, 256, 0, stream>>>(hin, rp, ci, dsrc, ddst, mbf, enc);
        gemm_bt_k<0><<<dim3(64, 4), 256, 0, stream>>>(mbf, Wt + (size_t)layer * HH * HH, hpre,
                                                      b + layer * HH, ain + layer, nullptr, nullptr);
        colstats_k<<<64, 512, 0, stream>>>(hpre, psum, psq);
        make_st_k<<<1, 512, 0, stream>>>(psum, psq, g + layer * HH, bbp + layer * HH, sc, sh);
        bn_apply_k<<<2048, 256, 0, stream>>>(hpre, sc, sh, aout + layer, hout);
    };

    // path 1: masked x through enc (list1) then dec1 (list1)
    run_layer(x, hA, rp1, col1, dsrc1, ddst1, 1, wtE, enc_b, enc_ain, enc_g, enc_bb, enc_aout, 0);
    run_layer(hA, hB, rp1, col1, dsrc1, ddst1, 1, wtE, enc_b, enc_ain, enc_g, enc_bb, enc_aout, 1);
    run_layer(hB, hA, rp1, col1, nullptr, nullptr, 0, wtD1, d1_b, d1_ain, d1_g, d1_bb, d1_aout, 0);
    run_layer(hA, hB, rp1, col1, nullptr, nullptr, 0, wtD1, d1_b, d1_ain, d1_g, d1_bb, d1_aout, 1);
    loss1_k<<<NN / 4, 256, 0, stream>>>(hB, attr, loss_acc);

    // path 2: attr through enc (list2) then dec2 (list2)
    run_layer(attr, hA, rp2, col2, dsrc2, ddst2, 1, wtE, enc_b, enc_ain, enc_g, enc_bb, enc_aout, 0);
    run_layer(hA, hB, rp2, col2, dsrc2, ddst2, 1, wtE, enc_b, enc_ain, enc_g, enc_bb, enc_aout, 1);
    run_layer(hB, hA, rp2, col2, nullptr, nullptr, 0, wtD2, d2_b, d2_ain, d2_g, d2_bb, d2_aout, 0);
    run_layer(hA, hB, rp2, col2, nullptr, nullptr, 0, wtD2, d2_b, d2_ain, d2_g, d2_bb, d2_aout, 1);
    l2n_bf_k<<<NN / 4, 256, 0, stream>>>(hB, h2n);
    gemm_bt_k<1><<<dim3(64, 64), 256, 0, stream>>>(h2n, h2n, nullptr, nullptr, nullptr, matrix, loss_acc + 1);

    final_k<<<1, 1, 0, stream>>>(loss_acc, (float*)d_out);
}

// Round 2
// 1226.038 us; speedup vs baseline: 1.1923x; 1.1923x over previous
//
#include <hip/hip_runtime.h>
#include <hip/hip_bf16.h>
#include <stdint.h>

#define NN 8192
#define HH 512

typedef __attribute__((ext_vector_type(4))) float f32x4;
typedef __attribute__((ext_vector_type(8))) __bf16 bf16x8;

__device__ __forceinline__ unsigned short f2bf(float f) {
    union { float f; unsigned int u; } c; c.f = f;
    unsigned int u = c.u;
    return (unsigned short)((u + 0x7FFFu + ((u >> 16) & 1u)) >> 16);
}
__device__ __forceinline__ unsigned int pk2(float a, float b) {
    return (unsigned int)f2bf(a) | ((unsigned int)f2bf(b) << 16);
}
__device__ __forceinline__ float bflo(unsigned int u) {
    union { unsigned int u; float f; } c; c.u = u << 16; return c.f;
}
__device__ __forceinline__ float bfhi(unsigned int u) {
    union { unsigned int u; float f; } c; c.u = u & 0xffff0000u; return c.f;
}
__device__ __forceinline__ uint4 pack8(float4 v0, float4 v1) {
    uint4 o;
    o.x = pk2(v0.x, v0.y); o.y = pk2(v0.z, v0.w);
    o.z = pk2(v1.x, v1.y); o.w = pk2(v1.z, v1.w);
    return o;
}

// async global -> LDS, 16B per lane; lds dest must be wave-uniform base (lane*16 implied)
__device__ __forceinline__ void gload16(const void* g, void* l) {
    __builtin_amdgcn_global_load_lds(
        (const __attribute__((address_space(1))) unsigned int*)(uintptr_t)g,
        (__attribute__((address_space(3))) unsigned int*)(uintptr_t)l, 16, 0, 0);
}

// ---------------- graph prep ----------------

__global__ void count_all_k(const int* __restrict__ s1, const int* __restrict__ d1, int E1,
                            const int* __restrict__ s2, const int* __restrict__ d2, int E2,
                            int* __restrict__ c1s, int* __restrict__ c1d,
                            int* __restrict__ c2s, int* __restrict__ c2d) {
    int i = blockIdx.x * blockDim.x + threadIdx.x;
    if (i < E1) {
        atomicAdd(&c1s[s1[i]], 1);
        atomicAdd(&c1d[d1[i]], 1);
    } else if (i < E1 + E2) {
        int j = i - E1;
        atomicAdd(&c2s[s2[j]], 1);
        atomicAdd(&c2d[d2[j]], 1);
    }
}

__global__ void dinv4_k(const int* c1s, const int* c1d, const int* c2s, const int* c2d,
                        float* d1s, float* d1d, float* d2s, float* d2d) {
    int n = blockIdx.x * blockDim.x + threadIdx.x;
    if (n < NN) {
        d1s[n] = rsqrtf(fmaxf((float)c1s[n], 1.f));
        d1d[n] = rsqrtf(fmaxf((float)c1d[n], 1.f));
        d2s[n] = rsqrtf(fmaxf((float)c2s[n], 1.f));
        d2d[n] = rsqrtf(fmaxf((float)c2d[n], 1.f));
    }
}

// exclusive scan of 8192 ints; blockIdx.x picks list; also writes woff
__global__ void scan2_k(const int* __restrict__ c1, int* __restrict__ r1, int* __restrict__ w1,
                        const int* __restrict__ c2, int* __restrict__ r2, int* __restrict__ w2) {
    const int* cnt = blockIdx.x ? c2 : c1;
    int* rp = blockIdx.x ? r2 : r1;
    int* wo = blockIdx.x ? w2 : w1;
    __shared__ int ts[1024];
    int t = threadIdx.x;
    int base = t * 8;
    int loc[8]; int s = 0;
#pragma unroll
    for (int j = 0; j < 8; j++) { loc[j] = s; s += cnt[base + j]; }
    ts[t] = s;
    __syncthreads();
    for (int off = 1; off < 1024; off <<= 1) {
        int v = 0;
        if (t >= off) v = ts[t - off];
        __syncthreads();
        if (t >= off) ts[t] += v;
        __syncthreads();
    }
    int pre = (t == 0) ? 0 : ts[t - 1];
#pragma unroll
    for (int j = 0; j < 8; j++) { rp[base + j] = pre + loc[j]; wo[base + j] = pre + loc[j]; }
    if (t == 1023) rp[8192] = ts[1023];
}

__global__ void fill_all_k(const int* __restrict__ s1, const int* __restrict__ d1, int E1,
                           const int* __restrict__ s2, const int* __restrict__ d2, int E2,
                           int* __restrict__ w1, int* __restrict__ col1,
                           int* __restrict__ w2, int* __restrict__ col2) {
    int i = blockIdx.x * blockDim.x + threadIdx.x;
    if (i < E1) {
        int p = atomicAdd(&w1[d1[i]], 1);
        col1[p] = s1[i];
    } else if (i < E1 + E2) {
        int j = i - E1;
        int p = atomicAdd(&w2[d2[j]], 1);
        col2[p] = s2[j];
    }
}

// ---------------- input build (bf16) ----------------

// attr f32 -> abf (bf16) and xbf (bf16) in one pass
__global__ void cvt2_k(const float4* __restrict__ a, uint4* __restrict__ o1, uint4* __restrict__ o2) {
    int nchunk = NN * HH / 8;
    for (int i = blockIdx.x * blockDim.x + threadIdx.x; i < nchunk; i += gridDim.x * blockDim.x) {
        float4 v0 = a[i * 2], v1 = a[i * 2 + 1];
        uint4 o = pack8(v0, v1);
        o1[i] = o;
        o2[i] = o;
    }
}

__global__ void set_noise_k(const int* __restrict__ nn, const int* __restrict__ ns,
                            const float4* __restrict__ attr4, uint4* __restrict__ xbf4) {
    int b = blockIdx.x, t = threadIdx.x; // 64 threads
    int d = nn[b], s = ns[b];
    float4 v0 = attr4[(size_t)s * 128 + t * 2], v1 = attr4[(size_t)s * 128 + t * 2 + 1];
    xbf4[(size_t)d * 64 + t] = pack8(v0, v1);
}

__global__ void set_token_k(const int* __restrict__ tn, const float4* __restrict__ m4,
                            uint4* __restrict__ xbf4) {
    int b = blockIdx.x, t = threadIdx.x; // 64 threads
    float4 v0 = m4[t * 2], v1 = m4[t * 2 + 1];
    xbf4[(size_t)tn[b] * 64 + t] = pack8(v0, v1);
}

// transpose W (l,H,H) f32 -> Wt (l, col, k) bf16 for 6 layers: 0,1=enc 2,3=dec1 4,5=dec2
__global__ void wtrans6_k(const float* __restrict__ W0, const float* __restrict__ W1,
                          const float* __restrict__ W2, unsigned short* __restrict__ Wt) {
    __shared__ float tile[32][33];
    int z = blockIdx.z;
    const float* Wl = (z < 2 ? W0 : z < 4 ? W1 : W2) + (size_t)(z & 1) * HH * HH;
    unsigned short* Wtl = Wt + (size_t)z * HH * HH;
    int k0 = blockIdx.x * 32, j0 = blockIdx.y * 32;
    for (int i = threadIdx.y; i < 32; i += 8)
        tile[i][threadIdx.x] = Wl[(size_t)(k0 + i) * HH + j0 + threadIdx.x];
    __syncthreads();
    for (int i = threadIdx.y; i < 32; i += 8)
        Wtl[(size_t)(j0 + i) * HH + k0 + threadIdx.x] = f2bf(tile[threadIdx.x][i]);
}

// ---------------- SpMM: m[dst] = sum over edges of h[src] (bf16 gather, f32 acc) ----------------

template <int ENC>
__global__ __launch_bounds__(256) void spmm_k(
    const unsigned short* __restrict__ h, const int* __restrict__ rp, const int* __restrict__ ci,
    const float* __restrict__ dsrc, const float* __restrict__ ddst,
    unsigned short* __restrict__ mout) {
    int lane = threadIdx.x & 63;
    int n = blockIdx.x * 4 + (threadIdx.x >> 6);
    int beg = rp[n], end = rp[n + 1];
    const uint4* h4 = (const uint4*)h;
    float a0 = 0, a1 = 0, a2 = 0, a3 = 0, a4 = 0, a5 = 0, a6 = 0, a7 = 0;
    for (int e = beg; e < end; ++e) {
        int s = ci[e];
        float w = ENC ? dsrc[s] : 1.0f;
        uint4 v = h4[(size_t)s * 64 + lane];
        if (ENC) {
            a0 += bflo(v.x) * w; a1 += bfhi(v.x) * w;
            a2 += bflo(v.y) * w; a3 += bfhi(v.y) * w;
            a4 += bflo(v.z) * w; a5 += bfhi(v.z) * w;
            a6 += bflo(v.w) * w; a7 += bfhi(v.w) * w;
        } else {
            a0 += bflo(v.x); a1 += bfhi(v.x);
            a2 += bflo(v.y); a3 += bfhi(v.y);
            a4 += bflo(v.z); a5 += bfhi(v.z);
            a6 += bflo(v.w); a7 += bfhi(v.w);
        }
    }
    float sc = ENC ? ddst[n] : 1.0f;
    uint4 o;
    o.x = pk2(a0 * sc, a1 * sc); o.y = pk2(a2 * sc, a3 * sc);
    o.z = pk2(a4 * sc, a5 * sc); o.w = pk2(a6 * sc, a7 * sc);
    ((uint4*)(mout + (size_t)n * 512))[lane] = o;
}

// ---------------- GEMM: C = A(Mx512) @ Bt(Nx512)^T via mfma 16x16x32 bf16 ----------------
// MODE 0 (BM=64): bias + prelu -> hpre f32, fused column sum/sumsq atomics.
// MODE 1 (BM=128): accumulate (C - matrix)^2 into loss_p; XCD-swizzled 1-D grid.

template <int BM, int MODE>
__global__ __launch_bounds__(256) void gemm_k(
    const unsigned short* __restrict__ A, const unsigned short* __restrict__ Bt,
    float* __restrict__ Cout, const float* __restrict__ bias, const float* __restrict__ ain_p,
    float* __restrict__ colsum, float* __restrict__ colsq,
    const float* __restrict__ matrix, float* __restrict__ loss_p) {
    constexpr int WS = BM / 2;   // wave subtile dim
    constexpr int FR = WS / 16;  // frags per dim
    __shared__ unsigned short sA[BM * 32];
    __shared__ unsigned short sB[BM * 32];
    int tid = threadIdx.x, lane = tid & 63, wid = tid >> 6;
    int wm = wid >> 1, wn = wid & 1;

    int bm, bn;
    if (MODE == 1) {
        int b = blockIdx.x;                    // 4096 blocks, %8==0 -> simple bijective swizzle
        int swz = (b & 7) * 512 + (b >> 3);
        bm = swz >> 6; bn = swz & 63;
    } else {
        bm = blockIdx.x; bn = blockIdx.y;
    }
    size_t row0 = (size_t)bm * BM, col0 = (size_t)bn * BM;

    f32x4 acc[FR][FR];
#pragma unroll
    for (int i = 0; i < FR; i++)
#pragma unroll
        for (int j = 0; j < FR; j++) acc[i][j] = f32x4{0.f, 0.f, 0.f, 0.f};

    for (int k0 = 0; k0 < 512; k0 += 32) {
#pragma unroll
        for (int s = wid; s < BM / 16; s += 4) {
            int q = s * 64 + lane;
            int r = q >> 2, c = q & 3;
            gload16(A + (row0 + r) * 512 + k0 + c * 8, sA + s * 512);
            gload16(Bt + (col0 + r) * 512 + k0 + c * 8, sB + s * 512);
        }
        __syncthreads();   // drains vmcnt: gload_lds complete
        bf16x8 af[FR], bfv[FR];
#pragma unroll
        for (int mi = 0; mi < FR; mi++) {
            union { uint4 u; bf16x8 v; } uu;
            uu.u = *(const uint4*)(sA + (wm * WS + mi * 16 + (lane & 15)) * 32 + (lane >> 4) * 8);
            af[mi] = uu.v;
        }
#pragma unroll
        for (int nj = 0; nj < FR; nj++) {
            union { uint4 u; bf16x8 v; } uu;
            uu.u = *(const uint4*)(sB + (wn * WS + nj * 16 + (lane & 15)) * 32 + (lane >> 4) * 8);
            bfv[nj] = uu.v;
        }
#pragma unroll
        for (int mi = 0; mi < FR; mi++)
#pragma unroll
            for (int nj = 0; nj < FR; nj++)
                acc[mi][nj] = __builtin_amdgcn_mfma_f32_16x16x32_bf16(af[mi], bfv[nj], acc[mi][nj], 0, 0, 0);
        __syncthreads();
    }

    if (MODE == 0) {
        float ain = ain_p[0];
        float ps[FR], pq[FR];
#pragma unroll
        for (int nj = 0; nj < FR; nj++) { ps[nj] = 0.f; pq[nj] = 0.f; }
#pragma unroll
        for (int mi = 0; mi < FR; mi++)
#pragma unroll
            for (int nj = 0; nj < FR; nj++) {
                size_t gr = row0 + wm * WS + mi * 16 + (lane >> 4) * 4;
                size_t gc = col0 + wn * WS + nj * 16 + (lane & 15);
                float bv = bias[gc];
#pragma unroll
                for (int r = 0; r < 4; r++) {
                    float v = acc[mi][nj][r] + bv;
                    v = (v >= 0.f) ? v : ain * v;
                    Cout[(gr + r) * 512 + gc] = v;
                    ps[nj] += v; pq[nj] += v * v;
                }
            }
        // block-level column reduction in LDS, then one atomic per column
        float* red = (float*)sA;
        if (tid < 2 * BM) red[tid] = 0.f;
        __syncthreads();
#pragma unroll
        for (int nj = 0; nj < FR; nj++) {
            int cl = wn * WS + nj * 16 + (lane & 15);
            atomicAdd(&red[cl], ps[nj]);
            atomicAdd(&red[BM + cl], pq[nj]);
        }
        __syncthreads();
        if (tid < BM) {
            atomicAdd(&colsum[col0 + tid], red[tid]);
            atomicAdd(&colsq[col0 + tid], red[BM + tid]);
        }
    } else {
        float ls = 0.f;
#pragma unroll
        for (int mi = 0; mi < FR; mi++)
#pragma unroll
            for (int nj = 0; nj < FR; nj++) {
                size_t gi = row0 + wm * WS + mi * 16 + (lane >> 4) * 4;
                size_t gj = col0 + wn * WS + nj * 16 + (lane & 15);
#pragma unroll
                for (int r = 0; r < 4; r++) {
                    float d = acc[mi][nj][r] - matrix[(gi + r) * NN + gj];
                    ls += d * d;
                }
            }
        for (int o = 32; o > 0; o >>= 1) ls += __shfl_xor(ls, o);
        if (lane == 0) atomicAdd(loss_p, ls);
    }
}

// ---------------- BN apply (scale/shift computed in-kernel) + PReLU -> bf16 ----------------

__global__ __launch_bounds__(256) void bn_apply_k(const float* __restrict__ hpre,
                                                  const float* __restrict__ cs, const float* __restrict__ cq,
                                                  const float* __restrict__ g, const float* __restrict__ bb,
                                                  const float* __restrict__ aout_p,
                                                  unsigned short* __restrict__ hout) {
    __shared__ float ssc[512], ssh[512];
    for (int c = threadIdx.x; c < 512; c += 256) {
        float mean = cs[c] * (1.f / 8192.f);
        float var = fmaxf(cq[c] * (1.f / 8192.f) - mean * mean, 0.f);
        float scale = rsqrtf(var + 1e-5f) * g[c];
        ssc[c] = scale;
        ssh[c] = bb[c] - mean * scale;
    }
    __syncthreads();
    float a = aout_p[0];
    const float4* hp = (const float4*)hpre;
    uint4* ho = (uint4*)hout;
    int nchunk = NN * HH / 8;
    for (int i = blockIdx.x * blockDim.x + threadIdx.x; i < nchunk; i += gridDim.x * blockDim.x) {
        int c0 = (i & 63) * 8;
        float4 v0 = hp[i * 2], v1 = hp[i * 2 + 1];
        float4 s0 = *(const float4*)&ssc[c0], s1 = *(const float4*)&ssc[c0 + 4];
        float4 t0 = *(const float4*)&ssh[c0], t1 = *(const float4*)&ssh[c0 + 4];
        float y0 = v0.x * s0.x + t0.x; y0 = (y0 >= 0.f) ? y0 : a * y0;
        float y1 = v0.y * s0.y + t0.y; y1 = (y1 >= 0.f) ? y1 : a * y1;
        float y2 = v0.z * s0.z + t0.z; y2 = (y2 >= 0.f) ? y2 : a * y2;
        float y3 = v0.w * s0.w + t0.w; y3 = (y3 >= 0.f) ? y3 : a * y3;
        float y4 = v1.x * s1.x + t1.x; y4 = (y4 >= 0.f) ? y4 : a * y4;
        float y5 = v1.y * s1.y + t1.y; y5 = (y5 >= 0.f) ? y5 : a * y5;
        float y6 = v1.z * s1.z + t1.z; y6 = (y6 >= 0.f) ? y6 : a * y6;
        float y7 = v1.w * s1.w + t1.w; y7 = (y7 >= 0.f) ? y7 : a * y7;
        uint4 o; o.x = pk2(y0, y1); o.y = pk2(y2, y3); o.z = pk2(y4, y5); o.w = pk2(y6, y7);
        ho[i] = o;
    }
}

// ---------------- losses ----------------

__global__ __launch_bounds__(256) void loss1_k(const unsigned short* __restrict__ h1,
                                               const float* __restrict__ attr, float* __restrict__ acc) {
    int lane = threadIdx.x & 63;
    int n = blockIdx.x * 4 + (threadIdx.x >> 6);
    uint4 va = ((const uint4*)(h1 + (size_t)n * 512))[lane];
    const float4* b = (const float4*)(attr + (size_t)n * 512);
    float4 vb0 = b[lane * 2], vb1 = b[lane * 2 + 1];
    float x0 = bflo(va.x), x1 = bfhi(va.x), x2 = bflo(va.y), x3 = bfhi(va.y);
    float x4 = bflo(va.z), x5 = bfhi(va.z), x6 = bflo(va.w), x7 = bfhi(va.w);
    float xx = x0*x0 + x1*x1 + x2*x2 + x3*x3 + x4*x4 + x5*x5 + x6*x6 + x7*x7;
    float yy = vb0.x*vb0.x + vb0.y*vb0.y + vb0.z*vb0.z + vb0.w*vb0.w
             + vb1.x*vb1.x + vb1.y*vb1.y + vb1.z*vb1.z + vb1.w*vb1.w;
    float xy = x0*vb0.x + x1*vb0.y + x2*vb0.z + x3*vb0.w
             + x4*vb1.x + x5*vb1.y + x6*vb1.z + x7*vb1.w;
    for (int o = 32; o > 0; o >>= 1) {
        xx += __shfl_xor(xx, o); yy += __shfl_xor(yy, o); xy += __shfl_xor(xy, o);
    }
    if (lane == 0) {
        float nx = fmaxf(sqrtf(xx), 1e-12f);
        float ny = fmaxf(sqrtf(yy), 1e-12f);
        float c = xy / (nx * ny);
        float d = 1.f - c;
        atomicAdd(acc, d * d * d);
    }
}

__global__ __launch_bounds__(256) void l2n_k(const unsigned short* __restrict__ h,
                                             unsigned short* __restrict__ out) {
    int lane = threadIdx.x & 63;
    int n = blockIdx.x * 4 + (threadIdx.x >> 6);
    uint4 va = ((const uint4*)(h + (size_t)n * 512))[lane];
    float x0 = bflo(va.x), x1 = bfhi(va.x), x2 = bflo(va.y), x3 = bfhi(va.y);
    float x4 = bflo(va.z), x5 = bfhi(va.z), x6 = bflo(va.w), x7 = bfhi(va.w);
    float ss = x0*x0 + x1*x1 + x2*x2 + x3*x3 + x4*x4 + x5*x5 + x6*x6 + x7*x7;
    for (int o = 32; o > 0; o >>= 1) ss += __shfl_xor(ss, o);
    float inv = 1.f / fmaxf(sqrtf(ss), 1e-12f);
    uint4 o;
    o.x = pk2(x0 * inv, x1 * inv); o.y = pk2(x2 * inv, x3 * inv);
    o.z = pk2(x4 * inv, x5 * inv); o.w = pk2(x6 * inv, x7 * inv);
    ((uint4*)(out + (size_t)n * 512))[lane] = o;
}

__global__ void final_k(const float* __restrict__ acc, float* __restrict__ out) {
    out[0] = 0.5f * (acc[0] / 8192.f) + 0.5f * (acc[1] / 67108864.f);
}

// ---------------- host ----------------

extern "C" void kernel_launch(void* const* d_in, const int* in_sizes, int n_in,
                              void* d_out, int out_size, void* d_ws, size_t ws_size,
                              hipStream_t stream) {
    const float* attr   = (const float*)d_in[0];
    const float* matrix = (const float*)d_in[1];
    const float* mask1  = (const float*)d_in[2];
    const int* src  = (const int*)d_in[3];
    const int* dst  = (const int*)d_in[4];
    const int* src2 = (const int*)d_in[5];
    const int* dst2 = (const int*)d_in[6];
    const int* token_nodes = (const int*)d_in[7];
    const int* noise_nodes = (const int*)d_in[8];
    const int* noise_src   = (const int*)d_in[9];
    const float* enc_W = (const float*)d_in[10];
    const float* enc_b = (const float*)d_in[11];
    const float* enc_ain = (const float*)d_in[12];
    const float* enc_g = (const float*)d_in[13];
    const float* enc_bb = (const float*)d_in[14];
    const float* enc_aout = (const float*)d_in[15];
    const float* d1_W = (const float*)d_in[16];
    const float* d1_b = (const float*)d_in[17];
    const float* d1_ain = (const float*)d_in[18];
    const float* d1_g = (const float*)d_in[19];
    const float* d1_bb = (const float*)d_in[20];
    const float* d1_aout = (const float*)d_in[21];
    const float* d2_W = (const float*)d_in[22];
    const float* d2_b = (const float*)d_in[23];
    const float* d2_ain = (const float*)d_in[24];
    const float* d2_g = (const float*)d_in[25];
    const float* d2_bb = (const float*)d_in[26];
    const float* d2_aout = (const float*)d_in[27];

    int EG = in_sizes[3], E2v = in_sizes[5], ntok = in_sizes[7], nnoise = in_sizes[8];

    char* w = (char*)d_ws;
    size_t off = 0;
    auto carve = [&](size_t bytes) -> void* {
        off = (off + 255) & ~(size_t)255;
        void* p = w + off;
        off += bytes;
        return p;
    };
    // zeroed prefix
    int* cnt1s = (int*)carve(NN * 4);
    int* cnt1d = (int*)carve(NN * 4);
    int* cnt2s = (int*)carve(NN * 4);
    int* cnt2d = (int*)carve(NN * 4);
    float* colsum = (float*)carve(8 * 512 * 4);   // per-layer-instance stats
    float* colsq  = (float*)carve(8 * 512 * 4);
    float* loss_acc = (float*)carve(256);
    size_t zero_end = off;

    int* rp1 = (int*)carve((NN + 1) * 4);
    int* rp2 = (int*)carve((NN + 1) * 4);
    int* woff1 = (int*)carve(NN * 4);
    int* woff2 = (int*)carve(NN * 4);
    float* dsrc1 = (float*)carve(NN * 4);
    float* ddst1 = (float*)carve(NN * 4);
    float* dsrc2 = (float*)carve(NN * 4);
    float* ddst2 = (float*)carve(NN * 4);
    int* col1 = (int*)carve((size_t)EG * 4);
    int* col2 = (int*)carve((size_t)E2v * 4);
    float* hpre = (float*)carve((size_t)NN * HH * 4);
    unsigned short* xbf = (unsigned short*)carve((size_t)NN * HH * 2);
    unsigned short* abf = (unsigned short*)carve((size_t)NN * HH * 2);
    unsigned short* hA = (unsigned short*)carve((size_t)NN * HH * 2);
    unsigned short* hB = (unsigned short*)carve((size_t)NN * HH * 2);
    unsigned short* mbf = (unsigned short*)carve((size_t)NN * HH * 2);
    unsigned short* h2n = (unsigned short*)carve((size_t)NN * HH * 2);
    unsigned short* Wt = (unsigned short*)carve((size_t)6 * HH * HH * 2);

    hipMemsetAsync(d_ws, 0, zero_end, stream);

    int ET = EG + E2v;
    count_all_k<<<(ET + 255) / 256, 256, 0, stream>>>(src, dst, EG, src2, dst2, E2v,
                                                      cnt1s, cnt1d, cnt2s, cnt2d);
    dinv4_k<<<NN / 256, 256, 0, stream>>>(cnt1s, cnt1d, cnt2s, cnt2d, dsrc1, ddst1, dsrc2, ddst2);
    scan2_k<<<2, 1024, 0, stream>>>(cnt1d, rp1, woff1, cnt2d, rp2, woff2);
    fill_all_k<<<(ET + 255) / 256, 256, 0, stream>>>(src, dst, EG, src2, dst2, E2v,
                                                     woff1, col1, woff2, col2);

    cvt2_k<<<1024, 256, 0, stream>>>((const float4*)attr, (uint4*)abf, (uint4*)xbf);
    set_noise_k<<<nnoise, 64, 0, stream>>>(noise_nodes, noise_src, (const float4*)attr, (uint4*)xbf);
    set_token_k<<<ntok, 64, 0, stream>>>(token_nodes, (const float4*)mask1, (uint4*)xbf);
    wtrans6_k<<<dim3(16, 16, 6), dim3(32, 8), 0, stream>>>(enc_W, d1_W, d2_W, Wt);

    auto run_layer = [&](const unsigned short* hin, unsigned short* hout,
                         const int* rp, const int* ci, const float* dsrc, const float* ddst, int enc,
                         int wlayer, const float* b, const float* ain,
                         const float* g, const float* bbp, const float* aout, int statIdx) {
        if (enc)
            spmm_k<1><<<NN / 4, 256, 0, stream>>>(hin, rp, ci, dsrc, ddst, mbf);
        else
            spmm_k<0><<<NN / 4, 256, 0, stream>>>(hin, rp, ci, dsrc, ddst, mbf);
        gemm_k<64, 0><<<dim3(128, 8), 256, 0, stream>>>(
            mbf, Wt + (size_t)wlayer * HH * HH, hpre, b, ain,
            colsum + statIdx * 512, colsq + statIdx * 512, nullptr, nullptr);
        bn_apply_k<<<256, 256, 0, stream>>>(hpre, colsum + statIdx * 512, colsq + statIdx * 512,
                                            g, bbp, aout, hout);
    };

    // path 1: masked x -> enc(list1) -> dec1(list1)
    run_layer(xbf, hA, rp1, col1, dsrc1, ddst1, 1, 0, enc_b,          enc_ain,     enc_g,          enc_bb,          enc_aout,     0);
    run_layer(hA, hB, rp1, col1, dsrc1, ddst1, 1, 1, enc_b + HH,      enc_ain + 1, enc_g + HH,     enc_bb + HH,     enc_aout + 1, 1);
    run_layer(hB, hA, rp1, col1, nullptr, nullptr, 0, 2, d1_b,        d1_ain,      d1_g,           d1_bb,           d1_aout,      2);
    run_layer(hA, hB, rp1, col1, nullptr, nullptr, 0, 3, d1_b + HH,   d1_ain + 1,  d1_g + HH,      d1_bb + HH,      d1_aout + 1,  3);
    loss1_k<<<NN / 4, 256, 0, stream>>>(hB, attr, loss_acc);

    // path 2: attr -> enc(list2) -> dec2(list2)
    run_layer(abf, hA, rp2, col2, dsrc2, ddst2, 1, 0, enc_b,          enc_ain,     enc_g,          enc_bb,          enc_aout,     4);
    run_layer(hA, hB, rp2, col2, dsrc2, ddst2, 1, 1, enc_b + HH,      enc_ain + 1, enc_g + HH,     enc_bb + HH,     enc_aout + 1, 5);
    run_layer(hB, hA, rp2, col2, nullptr, nullptr, 0, 4, d2_b,        d2_ain,      d2_g,           d2_bb,           d2_aout,      6);
    run_layer(hA, hB, rp2, col2, nullptr, nullptr, 0, 5, d2_b + HH,   d2_ain + 1,  d2_g + HH,      d2_bb + HH,      d2_aout + 1,  7);
    l2n_k<<<NN / 4, 256, 0, stream>>>(hB, h2n);
    gemm_k<128, 1><<<4096, 256, 0, stream>>>(h2n, h2n, nullptr, nullptr, nullptr,
                                             nullptr, nullptr, matrix, loss_acc + 1);

    final_k<<<1, 1, 0, stream>>>(loss_acc, (float*)d_out);
}

// Round 3
// 1143.619 us; speedup vs baseline: 1.2782x; 1.0721x over previous
//
#include <hip/hip_runtime.h>
#include <hip/hip_bf16.h>
#include <stdint.h>

#define NN 8192
#define HH 512

typedef __attribute__((ext_vector_type(4))) float f32x4;
typedef __attribute__((ext_vector_type(8))) __bf16 bf16x8;

__device__ __forceinline__ unsigned short f2bf(float f) {
    union { float f; unsigned int u; } c; c.f = f;
    unsigned int u = c.u;
    return (unsigned short)((u + 0x7FFFu + ((u >> 16) & 1u)) >> 16);
}
__device__ __forceinline__ unsigned int pk2(float a, float b) {
    return (unsigned int)f2bf(a) | ((unsigned int)f2bf(b) << 16);
}
__device__ __forceinline__ float bflo(unsigned int u) {
    union { unsigned int u; float f; } c; c.u = u << 16; return c.f;
}
__device__ __forceinline__ float bfhi(unsigned int u) {
    union { unsigned int u; float f; } c; c.u = u & 0xffff0000u; return c.f;
}
__device__ __forceinline__ uint4 pack8(float4 v0, float4 v1) {
    uint4 o;
    o.x = pk2(v0.x, v0.y); o.y = pk2(v0.z, v0.w);
    o.z = pk2(v1.x, v1.y); o.w = pk2(v1.z, v1.w);
    return o;
}

// async global -> LDS, 16B/lane; LDS dest wave-uniform base (+lane*16 implied)
__device__ __forceinline__ void gload16(const void* g, void* l) {
    __builtin_amdgcn_global_load_lds(
        (const __attribute__((address_space(1))) unsigned int*)(uintptr_t)g,
        (__attribute__((address_space(3))) unsigned int*)(uintptr_t)l, 16, 0, 0);
}

// ---------------- graph prep ----------------

__global__ void count_all_k(const int* __restrict__ s1, const int* __restrict__ d1, int E1,
                            const int* __restrict__ s2, const int* __restrict__ d2, int E2,
                            int* __restrict__ c1s, int* __restrict__ c1d,
                            int* __restrict__ c2s, int* __restrict__ c2d) {
    int i = blockIdx.x * blockDim.x + threadIdx.x;
    if (i < E1) {
        atomicAdd(&c1s[s1[i]], 1);
        atomicAdd(&c1d[d1[i]], 1);
    } else if (i < E1 + E2) {
        int j = i - E1;
        atomicAdd(&c2s[s2[j]], 1);
        atomicAdd(&c2d[d2[j]], 1);
    }
}

__global__ void dinv4_k(const int* c1s, const int* c1d, const int* c2s, const int* c2d,
                        float* d1s, float* d1d, float* d2s, float* d2d) {
    int n = blockIdx.x * blockDim.x + threadIdx.x;
    if (n < NN) {
        d1s[n] = rsqrtf(fmaxf((float)c1s[n], 1.f));
        d1d[n] = rsqrtf(fmaxf((float)c1d[n], 1.f));
        d2s[n] = rsqrtf(fmaxf((float)c2s[n], 1.f));
        d2d[n] = rsqrtf(fmaxf((float)c2d[n], 1.f));
    }
}

__global__ void scan2_k(const int* __restrict__ c1, int* __restrict__ r1, int* __restrict__ w1,
                        const int* __restrict__ c2, int* __restrict__ r2, int* __restrict__ w2) {
    const int* cnt = blockIdx.x ? c2 : c1;
    int* rp = blockIdx.x ? r2 : r1;
    int* wo = blockIdx.x ? w2 : w1;
    __shared__ int ts[1024];
    int t = threadIdx.x;
    int base = t * 8;
    int loc[8]; int s = 0;
#pragma unroll
    for (int j = 0; j < 8; j++) { loc[j] = s; s += cnt[base + j]; }
    ts[t] = s;
    __syncthreads();
    for (int off = 1; off < 1024; off <<= 1) {
        int v = 0;
        if (t >= off) v = ts[t - off];
        __syncthreads();
        if (t >= off) ts[t] += v;
        __syncthreads();
    }
    int pre = (t == 0) ? 0 : ts[t - 1];
#pragma unroll
    for (int j = 0; j < 8; j++) { rp[base + j] = pre + loc[j]; wo[base + j] = pre + loc[j]; }
    if (t == 1023) rp[8192] = ts[1023];
}

__global__ void fill_all_k(const int* __restrict__ s1, const int* __restrict__ d1, int E1,
                           const int* __restrict__ s2, const int* __restrict__ d2, int E2,
                           int* __restrict__ w1, int* __restrict__ col1,
                           int* __restrict__ w2, int* __restrict__ col2) {
    int i = blockIdx.x * blockDim.x + threadIdx.x;
    if (i < E1) {
        int p = atomicAdd(&w1[d1[i]], 1);
        col1[p] = s1[i];
    } else if (i < E1 + E2) {
        int j = i - E1;
        int p = atomicAdd(&w2[d2[j]], 1);
        col2[p] = s2[j];
    }
}

// ---------------- input build (bf16) ----------------

__global__ void cvt2_k(const float4* __restrict__ a, uint4* __restrict__ o1, uint4* __restrict__ o2) {
    int nchunk = NN * HH / 8;
    for (int i = blockIdx.x * blockDim.x + threadIdx.x; i < nchunk; i += gridDim.x * blockDim.x) {
        float4 v0 = a[i * 2], v1 = a[i * 2 + 1];
        uint4 o = pack8(v0, v1);
        o1[i] = o;
        o2[i] = o;
    }
}

__global__ void set_noise_k(const int* __restrict__ nn, const int* __restrict__ ns,
                            const float4* __restrict__ attr4, uint4* __restrict__ xbf4) {
    int b = blockIdx.x, t = threadIdx.x; // 64 threads
    int d = nn[b], s = ns[b];
    float4 v0 = attr4[(size_t)s * 128 + t * 2], v1 = attr4[(size_t)s * 128 + t * 2 + 1];
    xbf4[(size_t)d * 64 + t] = pack8(v0, v1);
}

__global__ void set_token_k(const int* __restrict__ tn, const float4* __restrict__ m4,
                            uint4* __restrict__ xbf4) {
    int b = blockIdx.x, t = threadIdx.x; // 64 threads
    float4 v0 = m4[t * 2], v1 = m4[t * 2 + 1];
    xbf4[(size_t)tn[b] * 64 + t] = pack8(v0, v1);
}

// W (l,H,H) f32 -> Wt (l, col, k) bf16, layers: 0,1=enc 2,3=dec1 4,5=dec2
__global__ void wtrans6_k(const float* __restrict__ W0, const float* __restrict__ W1,
                          const float* __restrict__ W2, unsigned short* __restrict__ Wt) {
    __shared__ float tile[32][33];
    int z = blockIdx.z;
    const float* Wl = (z < 2 ? W0 : z < 4 ? W1 : W2) + (size_t)(z & 1) * HH * HH;
    unsigned short* Wtl = Wt + (size_t)z * HH * HH;
    int k0 = blockIdx.x * 32, j0 = blockIdx.y * 32;
    for (int i = threadIdx.y; i < 32; i += 8)
        tile[i][threadIdx.x] = Wl[(size_t)(k0 + i) * HH + j0 + threadIdx.x];
    __syncthreads();
    for (int i = threadIdx.y; i < 32; i += 8)
        Wtl[(size_t)(j0 + i) * HH + k0 + threadIdx.x] = f2bf(tile[threadIdx.x][i]);
}

// ---------------- SpMM (bf16 gather, f32 acc, 2-edge unroll) ----------------

template <int ENC>
__global__ __launch_bounds__(256) void spmm_k(
    const unsigned short* __restrict__ h, const int* __restrict__ rp, const int* __restrict__ ci,
    const float* __restrict__ dsrc, const float* __restrict__ ddst,
    unsigned short* __restrict__ mout) {
    int lane = threadIdx.x & 63;
    int n = blockIdx.x * 4 + (threadIdx.x >> 6);
    int beg = rp[n], end = rp[n + 1];
    const uint4* h4 = (const uint4*)h;
    float a0 = 0, a1 = 0, a2 = 0, a3 = 0, a4 = 0, a5 = 0, a6 = 0, a7 = 0;
    float b0 = 0, b1 = 0, b2 = 0, b3 = 0, b4 = 0, b5 = 0, b6 = 0, b7 = 0;
    int e = beg;
    for (; e + 2 <= end; e += 2) {
        int s0 = ci[e], s1 = ci[e + 1];
        float w0 = ENC ? dsrc[s0] : 1.0f;
        float w1 = ENC ? dsrc[s1] : 1.0f;
        uint4 u = h4[(size_t)s0 * 64 + lane];
        uint4 v = h4[(size_t)s1 * 64 + lane];
        a0 += bflo(u.x) * w0; a1 += bfhi(u.x) * w0;
        a2 += bflo(u.y) * w0; a3 += bfhi(u.y) * w0;
        a4 += bflo(u.z) * w0; a5 += bfhi(u.z) * w0;
        a6 += bflo(u.w) * w0; a7 += bfhi(u.w) * w0;
        b0 += bflo(v.x) * w1; b1 += bfhi(v.x) * w1;
        b2 += bflo(v.y) * w1; b3 += bfhi(v.y) * w1;
        b4 += bflo(v.z) * w1; b5 += bfhi(v.z) * w1;
        b6 += bflo(v.w) * w1; b7 += bfhi(v.w) * w1;
    }
    if (e < end) {
        int s0 = ci[e];
        float w0 = ENC ? dsrc[s0] : 1.0f;
        uint4 u = h4[(size_t)s0 * 64 + lane];
        a0 += bflo(u.x) * w0; a1 += bfhi(u.x) * w0;
        a2 += bflo(u.y) * w0; a3 += bfhi(u.y) * w0;
        a4 += bflo(u.z) * w0; a5 += bfhi(u.z) * w0;
        a6 += bflo(u.w) * w0; a7 += bfhi(u.w) * w0;
    }
    a0 += b0; a1 += b1; a2 += b2; a3 += b3;
    a4 += b4; a5 += b5; a6 += b6; a7 += b7;
    float sc = ENC ? ddst[n] : 1.0f;
    uint4 o;
    o.x = pk2(a0 * sc, a1 * sc); o.y = pk2(a2 * sc, a3 * sc);
    o.z = pk2(a4 * sc, a5 * sc); o.w = pk2(a6 * sc, a7 * sc);
    ((uint4*)(mout + (size_t)n * 512))[lane] = o;
}

// ---------------- GEMM: C = A(Mx512) @ Bt(Nx512)^T, 2-phase pipelined, BK=64 ----------------
// LDS: linear dest for global_load_lds; source pre-swizzled chunk c = p ^ (r&7);
// ds_read chunk = (ks*4+q) ^ (row&7)  ->  rows 0..7 hit 8 distinct bank-quads.
// MODE 0 (BM=64): bias+prelu -> hpre f32 + fused col sum/sumsq atomics.
// MODE 1 (BM=128): accumulate (C - matrix)^2; XCD-bijective 1-D grid.

template <int BM, int MODE>
__global__ __launch_bounds__(256) void gemm_k(
    const unsigned short* __restrict__ A, const unsigned short* __restrict__ Bt,
    float* __restrict__ Cout, const float* __restrict__ bias, const float* __restrict__ ain_p,
    float* __restrict__ colsum, float* __restrict__ colsq,
    const float* __restrict__ matrix, float* __restrict__ loss_p) {
    constexpr int WS = BM / 2;
    constexpr int FR = WS / 16;
    constexpr int TILE_SH = BM * 64;  // shorts per operand tile (BK=64)
    __shared__ unsigned short sA[2][TILE_SH];
    __shared__ unsigned short sB[2][TILE_SH];
    int tid = threadIdx.x, lane = tid & 63, wid = tid >> 6;
    int wm = wid >> 1, wn = wid & 1;

    int bm, bn;
    if (MODE == 1) {
        int b = blockIdx.x;                 // 4096 blocks, %8==0 -> bijective swizzle
        int swz = (b & 7) * 512 + (b >> 3);
        bm = swz >> 6; bn = swz & 63;
    } else {
        bm = blockIdx.x; bn = blockIdx.y;
    }
    size_t row0 = (size_t)bm * BM, col0 = (size_t)bn * BM;
    const unsigned short* Ag = A + row0 * 512;
    const unsigned short* Bg = Bt + col0 * 512;

    f32x4 acc[FR][FR];
#pragma unroll
    for (int i = 0; i < FR; i++)
#pragma unroll
        for (int j = 0; j < FR; j++) acc[i][j] = f32x4{0.f, 0.f, 0.f, 0.f};

    int lr = lane >> 3, lp = lane & 7;  // stage: sub-row, chunk-slot

#define STAGE(buf, kt)                                                          \
    {                                                                           \
        _Pragma("unroll")                                                       \
        for (int s = wid; s < BM / 8; s += 4) {                                 \
            int r = s * 8 + lr;                                                 \
            int c = lp ^ (r & 7);                                               \
            gload16(Ag + (size_t)r * 512 + (kt) * 64 + c * 8, &sA[buf][s * 512]); \
            gload16(Bg + (size_t)r * 512 + (kt) * 64 + c * 8, &sB[buf][s * 512]); \
        }                                                                       \
    }

    STAGE(0, 0);
    __syncthreads();
    int cur = 0;
    constexpr int NT = 8;
#pragma unroll
    for (int kt = 0; kt < NT; ++kt) {
        if (kt + 1 < NT) STAGE(cur ^ 1, kt + 1);
        bf16x8 af[FR][2], bf[FR][2];
        int q = lane >> 4;
#pragma unroll
        for (int mi = 0; mi < FR; mi++) {
            int mr = wm * WS + mi * 16 + (lane & 15);
#pragma unroll
            for (int ks = 0; ks < 2; ks++) {
                int ch = (ks * 4 + q) ^ (mr & 7);
                union { uint4 u; bf16x8 v; } uu;
                uu.u = *(const uint4*)(&sA[cur][mr * 64 + ch * 8]);
                af[mi][ks] = uu.v;
            }
        }
#pragma unroll
        for (int nj = 0; nj < FR; nj++) {
            int nr = wn * WS + nj * 16 + (lane & 15);
#pragma unroll
            for (int ks = 0; ks < 2; ks++) {
                int ch = (ks * 4 + q) ^ (nr & 7);
                union { uint4 u; bf16x8 v; } uu;
                uu.u = *(const uint4*)(&sB[cur][nr * 64 + ch * 8]);
                bf[nj][ks] = uu.v;
            }
        }
#pragma unroll
        for (int ks = 0; ks < 2; ks++)
#pragma unroll
            for (int mi = 0; mi < FR; mi++)
#pragma unroll
                for (int nj = 0; nj < FR; nj++)
                    acc[mi][nj] = __builtin_amdgcn_mfma_f32_16x16x32_bf16(af[mi][ks], bf[nj][ks],
                                                                          acc[mi][nj], 0, 0, 0);
        if (kt + 1 < NT) __syncthreads();  // drains vmcnt: next tile staged
        cur ^= 1;
    }
#undef STAGE

    if (MODE == 0) {
        float ain = ain_p[0];
        float ps[FR], pq[FR];
#pragma unroll
        for (int nj = 0; nj < FR; nj++) { ps[nj] = 0.f; pq[nj] = 0.f; }
#pragma unroll
        for (int mi = 0; mi < FR; mi++)
#pragma unroll
            for (int nj = 0; nj < FR; nj++) {
                size_t gr = row0 + wm * WS + mi * 16 + (lane >> 4) * 4;
                size_t gc = col0 + wn * WS + nj * 16 + (lane & 15);
                float bv = bias[gc];
#pragma unroll
                for (int r = 0; r < 4; r++) {
                    float v = acc[mi][nj][r] + bv;
                    v = (v >= 0.f) ? v : ain * v;
                    Cout[(gr + r) * 512 + gc] = v;
                    ps[nj] += v; pq[nj] += v * v;
                }
            }
        __syncthreads();
        float* red = (float*)&sA[0][0];
        if (tid < 2 * BM) red[tid] = 0.f;
        __syncthreads();
#pragma unroll
        for (int nj = 0; nj < FR; nj++) {
            int cl = wn * WS + nj * 16 + (lane & 15);
            atomicAdd(&red[cl], ps[nj]);
            atomicAdd(&red[BM + cl], pq[nj]);
        }
        __syncthreads();
        if (tid < BM) {
            atomicAdd(&colsum[col0 + tid], red[tid]);
            atomicAdd(&colsq[col0 + tid], red[BM + tid]);
        }
    } else {
        float ls = 0.f;
#pragma unroll
        for (int mi = 0; mi < FR; mi++)
#pragma unroll
            for (int nj = 0; nj < FR; nj++) {
                size_t gi = row0 + wm * WS + mi * 16 + (lane >> 4) * 4;
                size_t gj = col0 + wn * WS + nj * 16 + (lane & 15);
#pragma unroll
                for (int r = 0; r < 4; r++) {
                    float d = acc[mi][nj][r] - matrix[(gi + r) * NN + gj];
                    ls += d * d;
                }
            }
        for (int o = 32; o > 0; o >>= 1) ls += __shfl_xor(ls, o);
        if (lane == 0) atomicAdd(loss_p, ls);
    }
}

// ---------------- BN apply + PReLU -> bf16 ----------------

__global__ __launch_bounds__(256) void bn_apply_k(const float* __restrict__ hpre,
                                                  const float* __restrict__ cs, const float* __restrict__ cq,
                                                  const float* __restrict__ g, const float* __restrict__ bb,
                                                  const float* __restrict__ aout_p,
                                                  unsigned short* __restrict__ hout) {
    __shared__ float ssc[512], ssh[512];
    for (int c = threadIdx.x; c < 512; c += 256) {
        float mean = cs[c] * (1.f / 8192.f);
        float var = fmaxf(cq[c] * (1.f / 8192.f) - mean * mean, 0.f);
        float scale = rsqrtf(var + 1e-5f) * g[c];
        ssc[c] = scale;
        ssh[c] = bb[c] - mean * scale;
    }
    __syncthreads();
    float a = aout_p[0];
    const float4* hp = (const float4*)hpre;
    uint4* ho = (uint4*)hout;
    int nchunk = NN * HH / 8;
    for (int i = blockIdx.x * blockDim.x + threadIdx.x; i < nchunk; i += gridDim.x * blockDim.x) {
        int c0 = (i & 63) * 8;
        float4 v0 = hp[i * 2], v1 = hp[i * 2 + 1];
        float4 s0 = *(const float4*)&ssc[c0], s1 = *(const float4*)&ssc[c0 + 4];
        float4 t0 = *(const float4*)&ssh[c0], t1 = *(const float4*)&ssh[c0 + 4];
        float y0 = v0.x * s0.x + t0.x; y0 = (y0 >= 0.f) ? y0 : a * y0;
        float y1 = v0.y * s0.y + t0.y; y1 = (y1 >= 0.f) ? y1 : a * y1;
        float y2 = v0.z * s0.z + t0.z; y2 = (y2 >= 0.f) ? y2 : a * y2;
        float y3 = v0.w * s0.w + t0.w; y3 = (y3 >= 0.f) ? y3 : a * y3;
        float y4 = v1.x * s1.x + t1.x; y4 = (y4 >= 0.f) ? y4 : a * y4;
        float y5 = v1.y * s1.y + t1.y; y5 = (y5 >= 0.f) ? y5 : a * y5;
        float y6 = v1.z * s1.z + t1.z; y6 = (y6 >= 0.f) ? y6 : a * y6;
        float y7 = v1.w * s1.w + t1.w; y7 = (y7 >= 0.f) ? y7 : a * y7;
        uint4 o; o.x = pk2(y0, y1); o.y = pk2(y2, y3); o.z = pk2(y4, y5); o.w = pk2(y6, y7);
        ho[i] = o;
    }
}

// ---------------- losses ----------------

__global__ __launch_bounds__(256) void loss1_k(const unsigned short* __restrict__ h1,
                                               const float* __restrict__ attr, float* __restrict__ acc) {
    int lane = threadIdx.x & 63;
    int n = blockIdx.x * 4 + (threadIdx.x >> 6);
    uint4 va = ((const uint4*)(h1 + (size_t)n * 512))[lane];
    const float4* b = (const float4*)(attr + (size_t)n * 512);
    float4 vb0 = b[lane * 2], vb1 = b[lane * 2 + 1];
    float x0 = bflo(va.x), x1 = bfhi(va.x), x2 = bflo(va.y), x3 = bfhi(va.y);
    float x4 = bflo(va.z), x5 = bfhi(va.z), x6 = bflo(va.w), x7 = bfhi(va.w);
    float xx = x0*x0 + x1*x1 + x2*x2 + x3*x3 + x4*x4 + x5*x5 + x6*x6 + x7*x7;
    float yy = vb0.x*vb0.x + vb0.y*vb0.y + vb0.z*vb0.z + vb0.w*vb0.w
             + vb1.x*vb1.x + vb1.y*vb1.y + vb1.z*vb1.z + vb1.w*vb1.w;
    float xy = x0*vb0.x + x1*vb0.y + x2*vb0.z + x3*vb0.w
             + x4*vb1.x + x5*vb1.y + x6*vb1.z + x7*vb1.w;
    for (int o = 32; o > 0; o >>= 1) {
        xx += __shfl_xor(xx, o); yy += __shfl_xor(yy, o); xy += __shfl_xor(xy, o);
    }
    if (lane == 0) {
        float nx = fmaxf(sqrtf(xx), 1e-12f);
        float ny = fmaxf(sqrtf(yy), 1e-12f);
        float c = xy / (nx * ny);
        float d = 1.f - c;
        atomicAdd(acc, d * d * d);
    }
}

__global__ __launch_bounds__(256) void l2n_k(const unsigned short* __restrict__ h,
                                             unsigned short* __restrict__ out) {
    int lane = threadIdx.x & 63;
    int n = blockIdx.x * 4 + (threadIdx.x >> 6);
    uint4 va = ((const uint4*)(h + (size_t)n * 512))[lane];
    float x0 = bflo(va.x), x1 = bfhi(va.x), x2 = bflo(va.y), x3 = bfhi(va.y);
    float x4 = bflo(va.z), x5 = bfhi(va.z), x6 = bflo(va.w), x7 = bfhi(va.w);
    float ss = x0*x0 + x1*x1 + x2*x2 + x3*x3 + x4*x4 + x5*x5 + x6*x6 + x7*x7;
    for (int o = 32; o > 0; o >>= 1) ss += __shfl_xor(ss, o);
    float inv = 1.f / fmaxf(sqrtf(ss), 1e-12f);
    uint4 o;
    o.x = pk2(x0 * inv, x1 * inv); o.y = pk2(x2 * inv, x3 * inv);
    o.z = pk2(x4 * inv, x5 * inv); o.w = pk2(x6 * inv, x7 * inv);
    ((uint4*)(out + (size_t)n * 512))[lane] = o;
}

__global__ void final_k(const float* __restrict__ acc, float* __restrict__ out) {
    out[0] = 0.5f * (acc[0] / 8192.f) + 0.5f * (acc[1] / 67108864.f);
}

// ---------------- host ----------------

extern "C" void kernel_launch(void* const* d_in, const int* in_sizes, int n_in,
                              void* d_out, int out_size, void* d_ws, size_t ws_size,
                              hipStream_t stream) {
    const float* attr   = (const float*)d_in[0];
    const float* matrix = (const float*)d_in[1];
    const float* mask1  = (const float*)d_in[2];
    const int* src  = (const int*)d_in[3];
    const int* dst  = (const int*)d_in[4];
    const int* src2 = (const int*)d_in[5];
    const int* dst2 = (const int*)d_in[6];
    const int* token_nodes = (const int*)d_in[7];
    const int* noise_nodes = (const int*)d_in[8];
    const int* noise_src   = (const int*)d_in[9];
    const float* enc_W = (const float*)d_in[10];
    const float* enc_b = (const float*)d_in[11];
    const float* enc_ain = (const float*)d_in[12];
    const float* enc_g = (const float*)d_in[13];
    const float* enc_bb = (const float*)d_in[14];
    const float* enc_aout = (const float*)d_in[15];
    const float* d1_W = (const float*)d_in[16];
    const float* d1_b = (const float*)d_in[17];
    const float* d1_ain = (const float*)d_in[18];
    const float* d1_g = (const float*)d_in[19];
    const float* d1_bb = (const float*)d_in[20];
    const float* d1_aout = (const float*)d_in[21];
    const float* d2_W = (const float*)d_in[22];
    const float* d2_b = (const float*)d_in[23];
    const float* d2_ain = (const float*)d_in[24];
    const float* d2_g = (const float*)d_in[25];
    const float* d2_bb = (const float*)d_in[26];
    const float* d2_aout = (const float*)d_in[27];

    int EG = in_sizes[3], E2v = in_sizes[5], ntok = in_sizes[7], nnoise = in_sizes[8];

    char* w = (char*)d_ws;
    size_t off = 0;
    auto carve = [&](size_t bytes) -> void* {
        off = (off + 255) & ~(size_t)255;
        void* p = w + off;
        off += bytes;
        return p;
    };
    // zeroed prefix
    int* cnt1s = (int*)carve(NN * 4);
    int* cnt1d = (int*)carve(NN * 4);
    int* cnt2s = (int*)carve(NN * 4);
    int* cnt2d = (int*)carve(NN * 4);
    float* colsum = (float*)carve(8 * 512 * 4);
    float* colsq  = (float*)carve(8 * 512 * 4);
    float* loss_acc = (float*)carve(256);
    size_t zero_end = off;

    int* rp1 = (int*)carve((NN + 1) * 4);
    int* rp2 = (int*)carve((NN + 1) * 4);
    int* woff1 = (int*)carve(NN * 4);
    int* woff2 = (int*)carve(NN * 4);
    float* dsrc1 = (float*)carve(NN * 4);
    float* ddst1 = (float*)carve(NN * 4);
    float* dsrc2 = (float*)carve(NN * 4);
    float* ddst2 = (float*)carve(NN * 4);
    int* col1 = (int*)carve((size_t)EG * 4);
    int* col2 = (int*)carve((size_t)E2v * 4);
    float* hpre = (float*)carve((size_t)NN * HH * 4);
    unsigned short* xbf = (unsigned short*)carve((size_t)NN * HH * 2);
    unsigned short* abf = (unsigned short*)carve((size_t)NN * HH * 2);
    unsigned short* hA = (unsigned short*)carve((size_t)NN * HH * 2);
    unsigned short* hB = (unsigned short*)carve((size_t)NN * HH * 2);
    unsigned short* mbf = (unsigned short*)carve((size_t)NN * HH * 2);
    unsigned short* h2n = (unsigned short*)carve((size_t)NN * HH * 2);
    unsigned short* Wt = (unsigned short*)carve((size_t)6 * HH * HH * 2);

    hipMemsetAsync(d_ws, 0, zero_end, stream);

    int ET = EG + E2v;
    count_all_k<<<(ET + 255) / 256, 256, 0, stream>>>(src, dst, EG, src2, dst2, E2v,
                                                      cnt1s, cnt1d, cnt2s, cnt2d);
    dinv4_k<<<NN / 256, 256, 0, stream>>>(cnt1s, cnt1d, cnt2s, cnt2d, dsrc1, ddst1, dsrc2, ddst2);
    scan2_k<<<2, 1024, 0, stream>>>(cnt1d, rp1, woff1, cnt2d, rp2, woff2);
    fill_all_k<<<(ET + 255) / 256, 256, 0, stream>>>(src, dst, EG, src2, dst2, E2v,
                                                     woff1, col1, woff2, col2);

    cvt2_k<<<1024, 256, 0, stream>>>((const float4*)attr, (uint4*)abf, (uint4*)xbf);
    set_noise_k<<<nnoise, 64, 0, stream>>>(noise_nodes, noise_src, (const float4*)attr, (uint4*)xbf);
    set_token_k<<<ntok, 64, 0, stream>>>(token_nodes, (const float4*)mask1, (uint4*)xbf);
    wtrans6_k<<<dim3(16, 16, 6), dim3(32, 8), 0, stream>>>(enc_W, d1_W, d2_W, Wt);

    auto run_layer = [&](const unsigned short* hin, unsigned short* hout,
                         const int* rp, const int* ci, const float* dsrc, const float* ddst, int enc,
                         int wlayer, const float* b, const float* ain,
                         const float* g, const float* bbp, const float* aout, int statIdx) {
        if (enc)
            spmm_k<1><<<NN / 4, 256, 0, stream>>>(hin, rp, ci, dsrc, ddst, mbf);
        else
            spmm_k<0><<<NN / 4, 256, 0, stream>>>(hin, rp, ci, dsrc, ddst, mbf);
        gemm_k<64, 0><<<dim3(128, 8), 256, 0, stream>>>(
            mbf, Wt + (size_t)wlayer * HH * HH, hpre, b, ain,
            colsum + statIdx * 512, colsq + statIdx * 512, nullptr, nullptr);
        bn_apply_k<<<256, 256, 0, stream>>>(hpre, colsum + statIdx * 512, colsq + statIdx * 512,
                                            g, bbp, aout, hout);
    };

    // path 1: masked x -> enc(list1) -> dec1(list1)
    run_layer(xbf, hA, rp1, col1, dsrc1, ddst1, 1, 0, enc_b,        enc_ain,     enc_g,      enc_bb,      enc_aout,     0);
    run_layer(hA, hB, rp1, col1, dsrc1, ddst1, 1, 1, enc_b + HH,    enc_ain + 1, enc_g + HH, enc_bb + HH, enc_aout + 1, 1);
    run_layer(hB, hA, rp1, col1, nullptr, nullptr, 0, 2, d1_b,      d1_ain,      d1_g,       d1_bb,       d1_aout,      2);
    run_layer(hA, hB, rp1, col1, nullptr, nullptr, 0, 3, d1_b + HH, d1_ain + 1,  d1_g + HH,  d1_bb + HH,  d1_aout + 1,  3);
    loss1_k<<<NN / 4, 256, 0, stream>>>(hB, attr, loss_acc);

    // path 2: attr -> enc(list2) -> dec2(list2)
    run_layer(abf, hA, rp2, col2, dsrc2, ddst2, 1, 0, enc_b,        enc_ain,     enc_g,      enc_bb,      enc_aout,     4);
    run_layer(hA, hB, rp2, col2, dsrc2, ddst2, 1, 1, enc_b + HH,    enc_ain + 1, enc_g + HH, enc_bb + HH, enc_aout + 1, 5);
    run_layer(hB, hA, rp2, col2, nullptr, nullptr, 0, 4, d2_b,      d2_ain,      d2_g,       d2_bb,       d2_aout,      6);
    run_layer(hA, hB, rp2, col2, nullptr, nullptr, 0, 5, d2_b + HH, d2_ain + 1,  d2_g + HH,  d2_bb + HH,  d2_aout + 1,  7);
    l2n_k<<<NN / 4, 256, 0, stream>>>(hB, h2n);
    gemm_k<128, 1><<<4096, 256, 0, stream>>>(h2n, h2n, nullptr, nullptr, nullptr,
                                             nullptr, nullptr, matrix, loss_acc + 1);

    final_k<<<1, 1, 0, stream>>>(loss_acc, (float*)d_out);
}